// Round 4
// baseline (691.661 us; speedup 1.0000x reference)
//
#include <hip/hip_runtime.h>
#include <stdint.h>

#define FH 64
#define FW 64
#define CIN 1536
#define C3C 512
#define C4C 1024
#define COUT 512
#define BATCH 16
#define NPIX 4096
#define NBOX 10
#define NSLICE 8

typedef short v8s __attribute__((ext_vector_type(8)));
typedef float v4f __attribute__((ext_vector_type(4)));
typedef unsigned short u8s __attribute__((ext_vector_type(8)));

__device__ __forceinline__ unsigned short f32_to_bf16(float f) {
    union { float f; uint32_t u; } v; v.f = f;
    uint32_t u = v.u;
    uint32_t r = (u + 0x7FFFu + ((u >> 16) & 1u)) >> 16;
    return (unsigned short)r;
}
__device__ __forceinline__ float bf16_to_f32(unsigned short h) {
    union { uint32_t u; float f; } v; v.u = ((uint32_t)h) << 16;
    return v.f;
}
__device__ __forceinline__ uint32_t pack_bf16(float a, float b) {
    return (uint32_t)f32_to_bf16(a) | ((uint32_t)f32_to_bf16(b) << 16);
}

// ---------------- BN constant folding -------------------------------------
__global__ void prep_bn(const float* __restrict__ bng, const float* __restrict__ bnb,
                        const float* __restrict__ bnm, const float* __restrict__ bnv,
                        const float* __restrict__ bconv,
                        float* __restrict__ scale, float* __restrict__ shift) {
    int o = threadIdx.x;
    if (o < COUT) {
        float inv = bng[o] / sqrtf(bnv[o] + 1e-5f);
        scale[o] = inv;
        shift[o] = bnb[o] + inv * (bconv[o] - bnm[o]);
    }
}

// ---------------- W f32 -> bf16 -------------------------------------------
__global__ void conv_w(const float* __restrict__ w, unsigned short* __restrict__ wbf, int n) {
    int i = blockIdx.x * 256 + threadIdx.x;
    if (i < n) wbf[i] = f32_to_bf16(w[i]);
}

// ---------------- c4 bilinear 2x upsample -> bf16 pixel-major --------------
// out c4uP[b][c][y*64+x]; half-pixel, clamp edges (== jax resize for 2x).
__global__ __launch_bounds__(256) void upsample_c4(const float* __restrict__ c4,
                                                   unsigned short* __restrict__ c4uP) {
    int t  = threadIdx.x;
    int c  = blockIdx.y;
    int b  = blockIdx.z;
    int y  = blockIdx.x * 32 + (t >> 3);
    int x0 = (t & 7) * 8;
    int jy = y >> 1;
    int jyB = jy + ((y & 1) ? 1 : -1);
    jyB = min(max(jyB, 0), 31);
    const float* r0 = c4 + ((size_t)(b * C4C + c) * 1024) + jy * 32;
    const float* r1 = c4 + ((size_t)(b * C4C + c) * 1024) + jyB * 32;
    int jx0 = x0 >> 1;
    float4 m0 = *(const float4*)(r0 + jx0);
    float4 m1 = *(const float4*)(r1 + jx0);
    int xl = max(jx0 - 1, 0), xr = min(jx0 + 4, 31);
    float q[6];
    q[0] = 0.75f * r0[xl] + 0.25f * r1[xl];
    q[1] = 0.75f * m0.x + 0.25f * m1.x;
    q[2] = 0.75f * m0.y + 0.25f * m1.y;
    q[3] = 0.75f * m0.z + 0.25f * m1.z;
    q[4] = 0.75f * m0.w + 0.25f * m1.w;
    q[5] = 0.75f * r0[xr] + 0.25f * r1[xr];
    u8s o;
    #pragma unroll
    for (int k = 0; k < 8; ++k) {
        int l = (k >> 1) + 1;
        float v = (k & 1) ? (0.75f * q[l] + 0.25f * q[l + 1])
                          : (0.75f * q[l] + 0.25f * q[l - 1]);
        o[k] = f32_to_bf16(v);
    }
    *(u8s*)(c4uP + (size_t)(b * C4C + c) * NPIX + y * FW + x0) = o;
}

// ---------------- GEMM + BN + ReLU, fused staging, channel-minor output ----
// attrT[b][pix][o] = relu(scale[o]*(fused[pix,:].W[o,:]) + shift[o])
// A-tile (weights) [128][40-pad], B-tile (pixels) [128][36-pad] in LDS.
__global__ __launch_bounds__(256) void gemm_bn_relu(
        const unsigned short* __restrict__ wbf,
        const float* __restrict__ c3,
        const unsigned short* __restrict__ c4uP,
        const float* __restrict__ scale, const float* __restrict__ shift,
        unsigned short* __restrict__ attrT) {
    __shared__ __align__(16) unsigned short lds_a[128 * 40];
    __shared__ __align__(16) unsigned short lds_b[128 * 36];
    int t  = threadIdx.x;
    int n0 = blockIdx.x * 128;   // pixel tile
    int o0 = blockIdx.y * 128;   // out-channel tile
    int b  = blockIdx.z;
    int wave = t >> 6, lane = t & 63;
    int wm = wave & 1, wn = wave >> 1;
    int quad = lane >> 4, l16 = lane & 15;

    v4f acc[4][4];
    #pragma unroll
    for (int i = 0; i < 4; ++i)
        #pragma unroll
        for (int j = 0; j < 4; ++j) acc[i][j] = (v4f)0.0f;

    // A staging: thread t covers rows (t>>2) and (t>>2)+64, 16B chunk (t&3)
    int sa_row = t >> 2, sa_q = t & 3;
    const uint4* asrc0 = (const uint4*)(wbf + (size_t)(o0 + sa_row) * CIN) + sa_q;
    const uint4* asrc1 = (const uint4*)(wbf + (size_t)(o0 + sa_row + 64) * CIN) + sa_q;
    uint4* adst0 = (uint4*)lds_a + sa_row * 5 + sa_q;
    uint4* adst1 = (uint4*)lds_a + (sa_row + 64) * 5 + sa_q;

    // B staging: thread t covers channel-pair cd=t&15 (ch 2cd,2cd+1),
    // pixels p0..p0+7 where p0=(t>>4)*8 (dword-transposed writes).
    int cd = t & 15;
    int p0 = (t >> 4) * 8;
    uint32_t* ldsb32 = (uint32_t*)lds_b;

    for (int kt = 0; kt < CIN / 32; ++kt) {
        uint4 a0 = asrc0[kt * 4];
        uint4 a1 = asrc1[kt * 4];
        uint32_t d[8];
        if (kt < 16) {           // c3 channels, f32 pixel-major
            const float* pa = c3 + (size_t)(b * C3C + kt * 32 + 2 * cd) * NPIX + n0 + p0;
            float4 x0 = *(const float4*)(pa);
            float4 x1 = *(const float4*)(pa + 4);
            float4 y0 = *(const float4*)(pa + NPIX);
            float4 y1 = *(const float4*)(pa + NPIX + 4);
            d[0] = pack_bf16(x0.x, y0.x); d[1] = pack_bf16(x0.y, y0.y);
            d[2] = pack_bf16(x0.z, y0.z); d[3] = pack_bf16(x0.w, y0.w);
            d[4] = pack_bf16(x1.x, y1.x); d[5] = pack_bf16(x1.y, y1.y);
            d[6] = pack_bf16(x1.z, y1.z); d[7] = pack_bf16(x1.w, y1.w);
        } else {                 // c4 upsampled, bf16 pixel-major
            const unsigned short* pa = c4uP + (size_t)(b * C4C + (kt - 16) * 32 + 2 * cd) * NPIX + n0 + p0;
            u8s ua = *(const u8s*)(pa);
            u8s ub = *(const u8s*)(pa + NPIX);
            #pragma unroll
            for (int j = 0; j < 8; ++j)
                d[j] = (uint32_t)ua[j] | ((uint32_t)ub[j] << 16);
        }
        __syncthreads();     // prev iter's fragment reads done
        adst0[0] = a0;
        adst1[0] = a1;
        #pragma unroll
        for (int j = 0; j < 8; ++j)
            ldsb32[(p0 + j) * 18 + cd] = d[j];
        __syncthreads();     // staging visible

        v8s pf[4], wf[4];
        #pragma unroll
        for (int i = 0; i < 4; ++i) {    // pixel fragments (M operand)
            int row = wm * 64 + i * 16 + l16;
            const uint32_t* pb = ldsb32 + row * 18 + quad * 4;
            union { v8s v; uint2 u[2]; } f;
            f.u[0] = *(const uint2*)(pb);
            f.u[1] = *(const uint2*)(pb + 2);
            pf[i] = f.v;
        }
        #pragma unroll
        for (int j = 0; j < 4; ++j)      // weight fragments (N operand)
            wf[j] = *(const v8s*)(lds_a + (wn * 64 + j * 16 + l16) * 40 + quad * 8);
        #pragma unroll
        for (int i = 0; i < 4; ++i)
            #pragma unroll
            for (int j = 0; j < 4; ++j)
                acc[i][j] = __builtin_amdgcn_mfma_f32_16x16x32_bf16(pf[i], wf[j], acc[i][j], 0, 0, 0);
    }

    unsigned short* ab = attrT + (size_t)b * NPIX * COUT;
    #pragma unroll
    for (int j = 0; j < 4; ++j) {
        int oo = o0 + wn * 64 + j * 16 + l16;
        float sc = scale[oo], sh = shift[oo];
        #pragma unroll
        for (int i = 0; i < 4; ++i) {
            int pbase = n0 + wm * 64 + i * 16 + quad * 4;
            #pragma unroll
            for (int r = 0; r < 4; ++r) {
                int pix = pbase + r;
                float v = acc[i][j][r] * sc + sh;
                v = fmaxf(v, 0.0f);
                ab[(size_t)pix * COUT + oo] = f32_to_bf16(v);
            }
        }
    }
}

// ---------------- ROI pool phase 1: per-(box, row-slice) partials ----------
__global__ __launch_bounds__(256) void roi_pool_partial(
        const unsigned short* __restrict__ attrT,
        const float* __restrict__ boxes,
        float* __restrict__ part) {
    int br = blockIdx.x;
    int sl = blockIdx.y;
    int b  = br / NBOX;
    int t  = threadIdx.x;
    const float* bx = boxes + (size_t)br * 4;
    int x1 = min(max((int)floorf(bx[0] * 0.125f), 0), 63);
    int y1 = min(max((int)floorf(bx[1] * 0.125f), 0), 63);
    int x2 = min(max((int)ceilf (bx[2] * 0.125f), 0), 63);
    int y2 = min(max((int)ceilf (bx[3] * 0.125f), 0), 63);
    if (x2 <= x1) x2 = min(x1 + 1, 64);
    if (y2 <= y1) y2 = min(y1 + 1, 64);
    int Lx = x2 - x1, Ly = y2 - y1;
    int sxk[5], exk[5], syk[5], eyk[5];
    float ivx[5], ivy[5];
    #pragma unroll
    for (int k = 0; k < 5; ++k) {
        sxk[k] = x1 + (k * Lx) / 5;
        exk[k] = x1 + ((k + 1) * Lx + 4) / 5;
        syk[k] = y1 + (k * Ly) / 5;
        eyk[k] = y1 + ((k + 1) * Ly + 4) / 5;
        ivx[k] = 1.0f / (float)(exk[k] - sxk[k]);
        ivy[k] = 1.0f / (float)(eyk[k] - syk[k]);
    }
    float a0[5][5] = {}, a1[5][5] = {};
    const uint32_t* base = (const uint32_t*)(attrT + (size_t)b * NPIX * COUT) + t;
    for (int h = y1 + sl; h < y2; h += NSLICE) {
        float s0[5] = {}, s1[5] = {};
        const uint32_t* row = base + (size_t)(h * FW) * (COUT / 2);
        for (int w = x1; w < x2; ++w) {
            uint32_t u = row[(size_t)w * (COUT / 2)];
            float v0 = bf16_to_f32((unsigned short)(u & 0xffffu));
            float v1 = bf16_to_f32((unsigned short)(u >> 16));
            #pragma unroll
            for (int q = 0; q < 5; ++q)
                if (w >= sxk[q] && w < exk[q]) {
                    s0[q] += ivx[q] * v0;
                    s1[q] += ivx[q] * v1;
                }
        }
        #pragma unroll
        for (int p = 0; p < 5; ++p)
            if (h >= syk[p] && h < eyk[p]) {
                #pragma unroll
                for (int q = 0; q < 5; ++q) {
                    a0[p][q] += ivy[p] * s0[q];
                    a1[p][q] += ivy[p] * s1[q];
                }
            }
    }
    int c0 = t * 2;
    float* op = part + ((size_t)sl * 160 * COUT + (size_t)br * COUT + c0) * 25;
    #pragma unroll
    for (int p = 0; p < 5; ++p)
        #pragma unroll
        for (int q = 0; q < 5; ++q) {
            op[p * 5 + q]      = a0[p][q];
            op[25 + p * 5 + q] = a1[p][q];
        }
}

// ---------------- ROI pool phase 2: reduce NSLICE partials -----------------
__global__ __launch_bounds__(256) void roi_pool_reduce(const float* __restrict__ part,
                                                       float* __restrict__ out) {
    const int n = 160 * COUT * 25;
    int i = blockIdx.x * 256 + threadIdx.x;
    if (i >= n) return;
    float s = 0.0f;
    #pragma unroll
    for (int sl = 0; sl < NSLICE; ++sl) s += part[(size_t)sl * n + i];
    out[640 + i] = s;
}

extern "C" void kernel_launch(void* const* d_in, const int* in_sizes, int n_in,
                              void* d_out, int out_size, void* d_ws, size_t ws_size,
                              hipStream_t stream) {
    const float* c3     = (const float*)d_in[0];
    const float* c4     = (const float*)d_in[1];
    const float* boxes  = (const float*)d_in[2];
    const float* w_conv = (const float*)d_in[3];
    const float* b_conv = (const float*)d_in[4];
    const float* bng    = (const float*)d_in[5];
    const float* bnb    = (const float*)d_in[6];
    const float* bnm    = (const float*)d_in[7];
    const float* bnv    = (const float*)d_in[8];
    float* out = (float*)d_out;

    char* ws = (char*)d_ws;
    // layout: c4uP bf16 [16][1024][4096] (134 MB) | wbf | scale | shift | attrT bf16 [16][4096][512]
    // part f32 [8][160][512][25] ALIASES c4uP (dead after gemm; stream-ordered).
    unsigned short* c4uP = (unsigned short*)ws;                        // 134217728 B
    float* part          = (float*)ws;                                 //  65536000 B (alias)
    unsigned short* wbf  = (unsigned short*)(ws + 201326592);          //   1572864 B
    float* scale         = (float*)(ws + 202899456);                   //      2048 B
    float* shift         = (float*)(ws + 202901504);                   //      2048 B
    unsigned short* attrT = (unsigned short*)(ws + 202903552);         //  67108864 B

    hipMemcpyAsync(d_out, d_in[2], 640 * sizeof(float), hipMemcpyDeviceToDevice, stream);
    prep_bn<<<1, 512, 0, stream>>>(bng, bnb, bnm, bnv, b_conv, scale, shift);
    conv_w<<<(COUT * CIN + 255) / 256, 256, 0, stream>>>(w_conv, wbf, COUT * CIN);
    upsample_c4<<<dim3(2, 1024, 16), 256, 0, stream>>>(c4, c4uP);
    gemm_bn_relu<<<dim3(32, 4, 16), 256, 0, stream>>>(wbf, c3, c4uP, scale, shift, attrT);
    roi_pool_partial<<<dim3(160, NSLICE), 256, 0, stream>>>(attrT, boxes, part);
    roi_pool_reduce<<<(160 * COUT * 25 + 255) / 256, 256, 0, stream>>>(part, out);
    (void)in_sizes; (void)n_in; (void)out_size; (void)ws_size;
}

// Round 5
// 636.943 us; speedup vs baseline: 1.0859x; 1.0859x over previous
//
#include <hip/hip_runtime.h>
#include <stdint.h>

#define FH 64
#define FW 64
#define CIN 1536
#define C3C 512
#define C4C 1024
#define COUT 512
#define BATCH 16
#define NPIX 4096
#define NBOX 10
#define NSLICE 8

typedef short v8s __attribute__((ext_vector_type(8)));
typedef float v4f __attribute__((ext_vector_type(4)));
typedef unsigned short u8s __attribute__((ext_vector_type(8)));

#define GLOAD_LDS16(g, l) __builtin_amdgcn_global_load_lds( \
    (const __attribute__((address_space(1))) void*)(g),     \
    (__attribute__((address_space(3))) void*)(l), 16, 0, 0)

__device__ __forceinline__ unsigned short f32_to_bf16(float f) {
    union { float f; uint32_t u; } v; v.f = f;
    uint32_t u = v.u;
    uint32_t r = (u + 0x7FFFu + ((u >> 16) & 1u)) >> 16;
    return (unsigned short)r;
}
__device__ __forceinline__ float bf16_to_f32(unsigned short h) {
    union { uint32_t u; float f; } v; v.u = ((uint32_t)h) << 16;
    return v.f;
}

// ---------------- BN constant folding -------------------------------------
__global__ void prep_bn(const float* __restrict__ bng, const float* __restrict__ bnb,
                        const float* __restrict__ bnm, const float* __restrict__ bnv,
                        const float* __restrict__ bconv,
                        float* __restrict__ scale, float* __restrict__ shift) {
    int o = threadIdx.x;
    if (o < COUT) {
        float inv = bng[o] / sqrtf(bnv[o] + 1e-5f);
        scale[o] = inv;
        shift[o] = bnb[o] + inv * (bconv[o] - bnm[o]);
    }
}

// ---------------- W f32 -> bf16 -------------------------------------------
__global__ void conv_w(const float* __restrict__ w, unsigned short* __restrict__ wbf, int n) {
    int i = blockIdx.x * 256 + threadIdx.x;
    if (i < n) wbf[i] = f32_to_bf16(w[i]);
}

// ---------------- build fusedT[b][pix][c] bf16 (K-major) -------------------
// One block per (ch-tile of 64, feature row y, batch). LDS transpose,
// vectorized 16-B stores (8 channels per store).
__global__ __launch_bounds__(256) void build_fusedT(const float* __restrict__ c3,
                                                    const float* __restrict__ c4,
                                                    unsigned short* __restrict__ fusedT) {
    __shared__ float lds[64][65];
    int ct = blockIdx.x;          // 0..23
    int y  = blockIdx.y;          // 0..63
    int b  = blockIdx.z;
    int t  = threadIdx.x;
    int c0 = ct * 64;
    int x  = t & 63;
    int r0 = t >> 6;              // 0..3

    if (c0 < C3C) {
        const float* src = c3 + (((size_t)(b * C3C + c0) * FH + y) * FW) + x;
        #pragma unroll
        for (int p = 0; p < 16; ++p) {
            int cr = r0 + p * 4;
            lds[cr][x] = src[(size_t)cr * (FH * FW)];
        }
    } else {
        int cc0 = c0 - C3C;
        int jy = y >> 1, fy = y & 1;
        int jyB = jy + (fy ? 1 : -1);
        jyB = min(max(jyB, 0), 31);
        int jx = x >> 1, fx = x & 1;
        int jxB = jx + (fx ? 1 : -1);
        jxB = min(max(jxB, 0), 31);
        const float* base = c4 + (size_t)(b * C4C + cc0) * (32 * 32);
        #pragma unroll
        for (int p = 0; p < 16; ++p) {
            int cr = r0 + p * 4;
            const float* pc = base + (size_t)cr * (32 * 32);
            float vA = pc[jy  * 32 + jx], vB = pc[jy  * 32 + jxB];
            float vC = pc[jyB * 32 + jx], vD = pc[jyB * 32 + jxB];
            lds[cr][x] = 0.75f * (0.75f * vA + 0.25f * vB)
                       + 0.25f * (0.75f * vC + 0.25f * vD);
        }
    }
    __syncthreads();
    // store phase: thread covers 2 chunks of (pixel, 8 channels)
    #pragma unroll
    for (int ii = 0; ii < 2; ++ii) {
        int id  = t + ii * 256;
        int pix = id >> 3;        // 0..63
        int cg  = id & 7;         // 0..7  (8-channel group)
        u8s o;
        #pragma unroll
        for (int k = 0; k < 8; ++k)
            o[k] = f32_to_bf16(lds[cg * 8 + k][pix]);
        *(u8s*)(fusedT + ((size_t)b * NPIX + y * FW + pix) * CIN + c0 + cg * 8) = o;
    }
}

// ---------------- GEMM + BN + ReLU (m97-style lds-DMA staging) -------------
// attrT[b][pix][o] = relu(scale[o]*(fused[pix,:].W[o,:]) + shift[o])
__global__ __launch_bounds__(256) void gemm_bn_relu(
        const unsigned short* __restrict__ wbf,
        const unsigned short* __restrict__ fusedT,
        const float* __restrict__ scale, const float* __restrict__ shift,
        unsigned short* __restrict__ attrT) {
    __shared__ __align__(16) unsigned short lds_a[128 * 32];  // W tile [o][k]
    __shared__ __align__(16) unsigned short lds_b[128 * 32];  // pix tile [pix][k]
    int t  = threadIdx.x;
    int n0 = blockIdx.x * 128;   // pixel tile
    int o0 = blockIdx.y * 128;   // out-channel tile
    int b  = blockIdx.z;
    int wave = t >> 6, lane = t & 63;
    int wm = wave & 1, wn = wave >> 1;
    int quad = lane >> 4, l16 = lane & 15;
    const unsigned short* fb = fusedT + (size_t)b * NPIX * CIN;

    v4f acc[4][4];
    #pragma unroll
    for (int i = 0; i < 4; ++i)
        #pragma unroll
        for (int j = 0; j < 4; ++j) acc[i][j] = (v4f)0.0f;

    // lds-DMA staging: instr0 covers rows t>>2 (0..63), instr1 rows +64;
    // 16-B chunk (t&3) of the 32-ch slice. LDS dst = wave base + lane*16.
    int row = t >> 2, cw = t & 3;
    const unsigned short* ga0 = wbf + (size_t)(o0 + row) * CIN + cw * 8;
    const unsigned short* ga1 = wbf + (size_t)(o0 + row + 64) * CIN + cw * 8;
    const unsigned short* gb0 = fb + (size_t)(n0 + row) * CIN + cw * 8;
    const unsigned short* gb1 = fb + (size_t)(n0 + row + 64) * CIN + cw * 8;
    unsigned short* la0 = lds_a + wave * 512;          // wave*1024 B
    unsigned short* la1 = lds_a + 2048 + wave * 512;
    unsigned short* lb0 = lds_b + wave * 512;
    unsigned short* lb1 = lds_b + 2048 + wave * 512;

    for (int kt = 0; kt < CIN / 32; ++kt) {
        __syncthreads();               // prev iter's fragment reads done
        GLOAD_LDS16(ga0, la0);
        GLOAD_LDS16(ga1, la1);
        GLOAD_LDS16(gb0, lb0);
        GLOAD_LDS16(gb1, lb1);
        ga0 += 32; ga1 += 32; gb0 += 32; gb1 += 32;
        __syncthreads();               // vmcnt drained -> tiles visible

        v8s pf[4], wf[4];
        #pragma unroll
        for (int i = 0; i < 4; ++i)      // pixel fragments (M operand)
            pf[i] = *(const v8s*)(lds_b + (wm * 64 + i * 16 + l16) * 32 + quad * 8);
        #pragma unroll
        for (int j = 0; j < 4; ++j)      // weight fragments (N operand)
            wf[j] = *(const v8s*)(lds_a + (wn * 64 + j * 16 + l16) * 32 + quad * 8);
        #pragma unroll
        for (int i = 0; i < 4; ++i)
            #pragma unroll
            for (int j = 0; j < 4; ++j)
                acc[i][j] = __builtin_amdgcn_mfma_f32_16x16x32_bf16(pf[i], wf[j], acc[i][j], 0, 0, 0);
    }

    unsigned short* ab = attrT + (size_t)b * NPIX * COUT;
    #pragma unroll
    for (int j = 0; j < 4; ++j) {
        int oo = o0 + wn * 64 + j * 16 + l16;
        float sc = scale[oo], sh = shift[oo];
        #pragma unroll
        for (int i = 0; i < 4; ++i) {
            int pbase = n0 + wm * 64 + i * 16 + quad * 4;
            #pragma unroll
            for (int r = 0; r < 4; ++r) {
                int pix = pbase + r;
                float v = acc[i][j][r] * sc + sh;
                v = fmaxf(v, 0.0f);
                ab[(size_t)pix * COUT + oo] = f32_to_bf16(v);
            }
        }
    }
}

// ---------------- ROI pool phase 1: per-(box, row-slice) partials ----------
// grid (160, NSLICE); thread t owns channels 2t, 2t+1. Output staged
// through LDS so global writes are coalesced float4s.
__global__ __launch_bounds__(256) void roi_pool_partial(
        const unsigned short* __restrict__ attrT,
        const float* __restrict__ boxes,
        float* __restrict__ part) {
    __shared__ float sbuf[256 * 50];
    int br = blockIdx.x;
    int sl = blockIdx.y;
    int b  = br / NBOX;
    int t  = threadIdx.x;
    const float* bx = boxes + (size_t)br * 4;
    int x1 = min(max((int)floorf(bx[0] * 0.125f), 0), 63);
    int y1 = min(max((int)floorf(bx[1] * 0.125f), 0), 63);
    int x2 = min(max((int)ceilf (bx[2] * 0.125f), 0), 63);
    int y2 = min(max((int)ceilf (bx[3] * 0.125f), 0), 63);
    if (x2 <= x1) x2 = min(x1 + 1, 64);
    if (y2 <= y1) y2 = min(y1 + 1, 64);
    int Lx = x2 - x1, Ly = y2 - y1;
    int sxk[5], exk[5], syk[5], eyk[5];
    float ivx[5], ivy[5];
    #pragma unroll
    for (int k = 0; k < 5; ++k) {
        sxk[k] = x1 + (k * Lx) / 5;
        exk[k] = x1 + ((k + 1) * Lx + 4) / 5;
        syk[k] = y1 + (k * Ly) / 5;
        eyk[k] = y1 + ((k + 1) * Ly + 4) / 5;
        ivx[k] = 1.0f / (float)(exk[k] - sxk[k]);
        ivy[k] = 1.0f / (float)(eyk[k] - syk[k]);
    }
    float a0[5][5] = {}, a1[5][5] = {};
    const uint32_t* base = (const uint32_t*)(attrT + (size_t)b * NPIX * COUT) + t;
    for (int h = y1 + sl; h < y2; h += NSLICE) {
        float s0[5] = {}, s1[5] = {};
        const uint32_t* row = base + (size_t)(h * FW) * (COUT / 2);
        for (int w = x1; w < x2; ++w) {
            uint32_t u = row[(size_t)w * (COUT / 2)];
            float v0 = bf16_to_f32((unsigned short)(u & 0xffffu));
            float v1 = bf16_to_f32((unsigned short)(u >> 16));
            #pragma unroll
            for (int q = 0; q < 5; ++q)
                if (w >= sxk[q] && w < exk[q]) {
                    s0[q] += ivx[q] * v0;
                    s1[q] += ivx[q] * v1;
                }
        }
        #pragma unroll
        for (int p = 0; p < 5; ++p)
            if (h >= syk[p] && h < eyk[p]) {
                #pragma unroll
                for (int q = 0; q < 5; ++q) {
                    a0[p][q] += ivy[p] * s0[q];
                    a1[p][q] += ivy[p] * s1[q];
                }
            }
    }
    // stage to LDS in the exact part layout: [c=2t][25] then [c=2t+1][25]
    #pragma unroll
    for (int p = 0; p < 5; ++p)
        #pragma unroll
        for (int q = 0; q < 5; ++q) {
            sbuf[t * 50 + p * 5 + q]      = a0[p][q];
            sbuf[t * 50 + 25 + p * 5 + q] = a1[p][q];
        }
    __syncthreads();
    float4* dst = (float4*)(part + ((size_t)sl * 160 + br) * (COUT * 25));
    const float4* src = (const float4*)sbuf;
    for (int i = t; i < (256 * 50) / 4; i += 256)
        dst[i] = src[i];
}

// ---------------- ROI pool phase 2: reduce NSLICE partials -----------------
__global__ __launch_bounds__(256) void roi_pool_reduce(const float* __restrict__ part,
                                                       float* __restrict__ out) {
    const int n = 160 * COUT * 25;
    int i = blockIdx.x * 256 + threadIdx.x;
    if (i >= n) return;
    float s = 0.0f;
    #pragma unroll
    for (int sl = 0; sl < NSLICE; ++sl) s += part[(size_t)sl * n + i];
    out[640 + i] = s;
}

extern "C" void kernel_launch(void* const* d_in, const int* in_sizes, int n_in,
                              void* d_out, int out_size, void* d_ws, size_t ws_size,
                              hipStream_t stream) {
    const float* c3     = (const float*)d_in[0];
    const float* c4     = (const float*)d_in[1];
    const float* boxes  = (const float*)d_in[2];
    const float* w_conv = (const float*)d_in[3];
    const float* b_conv = (const float*)d_in[4];
    const float* bng    = (const float*)d_in[5];
    const float* bnb    = (const float*)d_in[6];
    const float* bnm    = (const float*)d_in[7];
    const float* bnv    = (const float*)d_in[8];
    float* out = (float*)d_out;

    char* ws = (char*)d_ws;
    // layout: fusedT bf16 [16][4096][1536] | wbf | scale | shift | attrT bf16 [16][4096][512]
    // part f32 [8][160][512][25] ALIASES fusedT (dead after gemm; stream-ordered).
    unsigned short* fusedT = (unsigned short*)ws;                       // 201326592 B
    float* part            = (float*)ws;                                //  65536000 B (alias)
    unsigned short* wbf    = (unsigned short*)(ws + 201326592);         //   1572864 B
    float* scale           = (float*)(ws + 202899456);                  //      2048 B
    float* shift           = (float*)(ws + 202901504);                  //      2048 B
    unsigned short* attrT  = (unsigned short*)(ws + 202903552);         //  67108864 B

    hipMemcpyAsync(d_out, d_in[2], 640 * sizeof(float), hipMemcpyDeviceToDevice, stream);
    prep_bn<<<1, 512, 0, stream>>>(bng, bnb, bnm, bnv, b_conv, scale, shift);
    conv_w<<<(COUT * CIN + 255) / 256, 256, 0, stream>>>(w_conv, wbf, COUT * CIN);
    build_fusedT<<<dim3(24, 64, 16), 256, 0, stream>>>(c3, c4, fusedT);
    gemm_bn_relu<<<dim3(32, 4, 16), 256, 0, stream>>>(wbf, fusedT, scale, shift, attrT);
    roi_pool_partial<<<dim3(160, NSLICE), 256, 0, stream>>>(attrT, boxes, part);
    roi_pool_reduce<<<(160 * COUT * 25 + 255) / 256, 256, 0, stream>>>(part, out);
    (void)in_sizes; (void)n_in; (void)out_size; (void)ws_size;
}

// Round 6
// 541.147 us; speedup vs baseline: 1.2781x; 1.1770x over previous
//
#include <hip/hip_runtime.h>
#include <stdint.h>

#define FH 64
#define FW 64
#define CIN 1536
#define C3C 512
#define C4C 1024
#define COUT 512
#define BATCH 16
#define NPIX 4096
#define NBOX 10
#define MPAD 256   // 10 boxes * 25 bins = 250, padded

typedef short v8s __attribute__((ext_vector_type(8)));
typedef float v4f __attribute__((ext_vector_type(4)));
typedef unsigned short u8s __attribute__((ext_vector_type(8)));

#define GLOAD_LDS16(g, l) __builtin_amdgcn_global_load_lds( \
    (const __attribute__((address_space(1))) void*)(g),     \
    (__attribute__((address_space(3))) void*)(l), 16, 0, 0)

__device__ __forceinline__ unsigned short f32_to_bf16(float f) {
    union { float f; uint32_t u; } v; v.f = f;
    uint32_t u = v.u;
    uint32_t r = (u + 0x7FFFu + ((u >> 16) & 1u)) >> 16;
    return (unsigned short)r;
}

// ---------------- BN constant folding -------------------------------------
__global__ void prep_bn(const float* __restrict__ bng, const float* __restrict__ bnb,
                        const float* __restrict__ bnm, const float* __restrict__ bnv,
                        const float* __restrict__ bconv,
                        float* __restrict__ scale, float* __restrict__ shift) {
    int o = threadIdx.x;
    if (o < COUT) {
        float inv = bng[o] / sqrtf(bnv[o] + 1e-5f);
        scale[o] = inv;
        shift[o] = bnb[o] + inv * (bconv[o] - bnm[o]);
    }
}

// ---------------- W f32 -> bf16 -------------------------------------------
__global__ void conv_w(const float* __restrict__ w, unsigned short* __restrict__ wbf, int n) {
    int i = blockIdx.x * 256 + threadIdx.x;
    if (i < n) wbf[i] = f32_to_bf16(w[i]);
}

// ---------------- build fusedT[b][pix][c] bf16 (K-major) -------------------
__global__ __launch_bounds__(256) void build_fusedT(const float* __restrict__ c3,
                                                    const float* __restrict__ c4,
                                                    unsigned short* __restrict__ fusedT) {
    __shared__ float lds[64][65];
    int ct = blockIdx.x;          // 0..23
    int y  = blockIdx.y;          // 0..63
    int b  = blockIdx.z;
    int t  = threadIdx.x;
    int c0 = ct * 64;
    int x  = t & 63;
    int r0 = t >> 6;              // 0..3

    if (c0 < C3C) {
        const float* src = c3 + (((size_t)(b * C3C + c0) * FH + y) * FW) + x;
        #pragma unroll
        for (int p = 0; p < 16; ++p) {
            int cr = r0 + p * 4;
            lds[cr][x] = src[(size_t)cr * (FH * FW)];
        }
    } else {
        int cc0 = c0 - C3C;
        int jy = y >> 1, fy = y & 1;
        int jyB = jy + (fy ? 1 : -1);
        jyB = min(max(jyB, 0), 31);
        int jx = x >> 1, fx = x & 1;
        int jxB = jx + (fx ? 1 : -1);
        jxB = min(max(jxB, 0), 31);
        const float* base = c4 + (size_t)(b * C4C + cc0) * (32 * 32);
        #pragma unroll
        for (int p = 0; p < 16; ++p) {
            int cr = r0 + p * 4;
            const float* pc = base + (size_t)cr * (32 * 32);
            float vA = pc[jy  * 32 + jx], vB = pc[jy  * 32 + jxB];
            float vC = pc[jyB * 32 + jx], vD = pc[jyB * 32 + jxB];
            lds[cr][x] = 0.75f * (0.75f * vA + 0.25f * vB)
                       + 0.25f * (0.75f * vC + 0.25f * vD);
        }
    }
    __syncthreads();
    #pragma unroll
    for (int ii = 0; ii < 2; ++ii) {
        int id  = t + ii * 256;
        int pix = id >> 3;        // 0..63
        int cg  = id & 7;         // 0..7
        u8s o;
        #pragma unroll
        for (int k = 0; k < 8; ++k)
            o[k] = f32_to_bf16(lds[cg * 8 + k][pix]);
        *(u8s*)(fusedT + ((size_t)b * NPIX + y * FW + pix) * CIN + c0 + cg * 8) = o;
    }
}

// ---------------- GEMM + BN + ReLU, channel-major out, swizzled LDS --------
// attr[b][o][pix] = relu(scale[o]*(W[o,:].fused[pix,:]) + shift[o])
__global__ __launch_bounds__(256) void gemm_bn_relu(
        const unsigned short* __restrict__ wbf,
        const unsigned short* __restrict__ fusedT,
        const float* __restrict__ scale, const float* __restrict__ shift,
        unsigned short* __restrict__ attr) {
    __shared__ __align__(16) unsigned short lds_a[128 * 32];  // W tile [o][k] swizzled
    __shared__ __align__(16) unsigned short lds_b[128 * 32];  // pix tile [pix][k] swizzled
    int t  = threadIdx.x;
    int n0 = blockIdx.x * 128;   // pixel tile
    int o0 = blockIdx.y * 128;   // out-channel tile
    int b  = blockIdx.z;
    int wave = t >> 6, lane = t & 63;
    int wm = wave & 1, wn = wave >> 1;
    int quad = lane >> 4, l16 = lane & 15;
    const unsigned short* fb = fusedT + (size_t)b * NPIX * CIN;

    v4f acc[4][4];
    #pragma unroll
    for (int i = 0; i < 4; ++i)
        #pragma unroll
        for (int j = 0; j < 4; ++j) acc[i][j] = (v4f)0.0f;

    // staging: row t>>2 (and +64), 16-B chunk col swizzled by (row>>1)&3
    int row = t >> 2;
    int colsw = (t & 3) ^ ((t >> 3) & 3);
    const unsigned short* ga0 = wbf + (size_t)(o0 + row) * CIN + colsw * 8;
    const unsigned short* ga1 = wbf + (size_t)(o0 + row + 64) * CIN + colsw * 8;
    const unsigned short* gb0 = fb + (size_t)(n0 + row) * CIN + colsw * 8;
    const unsigned short* gb1 = fb + (size_t)(n0 + row + 64) * CIN + colsw * 8;
    unsigned short* la0 = lds_a + wave * 512;
    unsigned short* la1 = lds_a + 2048 + wave * 512;
    unsigned short* lb0 = lds_b + wave * 512;
    unsigned short* lb1 = lds_b + 2048 + wave * 512;

    int csw = (l16 >> 1) & 3;     // frag-read de-swizzle

    for (int kt = 0; kt < CIN / 32; ++kt) {
        __syncthreads();
        GLOAD_LDS16(ga0, la0);
        GLOAD_LDS16(ga1, la1);
        GLOAD_LDS16(gb0, lb0);
        GLOAD_LDS16(gb1, lb1);
        ga0 += 32; ga1 += 32; gb0 += 32; gb1 += 32;
        __syncthreads();

        v8s wf[4], pf[4];
        #pragma unroll
        for (int i = 0; i < 4; ++i)      // weight fragments (M operand: rows=o)
            wf[i] = *(const v8s*)(lds_a + (wm * 64 + i * 16 + l16) * 32 + (quad ^ csw) * 8);
        #pragma unroll
        for (int j = 0; j < 4; ++j)      // pixel fragments (N operand: cols=pix)
            pf[j] = *(const v8s*)(lds_b + (wn * 64 + j * 16 + l16) * 32 + (quad ^ csw) * 8);
        #pragma unroll
        for (int i = 0; i < 4; ++i)
            #pragma unroll
            for (int j = 0; j < 4; ++j)
                acc[i][j] = __builtin_amdgcn_mfma_f32_16x16x32_bf16(wf[i], pf[j], acc[i][j], 0, 0, 0);
    }

    unsigned short* ab = attr + (size_t)b * COUT * NPIX;
    #pragma unroll
    for (int i = 0; i < 4; ++i) {
        int obase = o0 + wm * 64 + i * 16 + quad * 4;
        #pragma unroll
        for (int r = 0; r < 4; ++r) {
            int oo = obase + r;
            float sc = scale[oo], sh = shift[oo];
            #pragma unroll
            for (int j = 0; j < 4; ++j) {
                int n = n0 + wn * 64 + j * 16 + l16;
                float v = acc[i][j][r] * sc + sh;
                v = fmaxf(v, 0.0f);
                ab[(size_t)oo * NPIX + n] = f32_to_bf16(v);
            }
        }
    }
}

// ---------------- build pooling matrix P[b][m][pix] bf16 -------------------
// m = box_in_batch*25 + p*5 + q; P = wy[p][y] * wx[q][x]. Rows 250..255 unused.
__global__ __launch_bounds__(256) void build_P(const float* __restrict__ boxes,
                                               unsigned short* __restrict__ P) {
    int br = blockIdx.x;                 // 0..159
    int b  = br / NBOX;
    int mb = (br % NBOX) * 25;
    int t  = threadIdx.x;
    int y  = t >> 2;                     // 0..63
    int x0 = (t & 3) * 16;               // 16 consecutive pixels in row y
    const float* bx = boxes + (size_t)br * 4;
    int x1 = min(max((int)floorf(bx[0] * 0.125f), 0), 63);
    int y1 = min(max((int)floorf(bx[1] * 0.125f), 0), 63);
    int x2 = min(max((int)ceilf (bx[2] * 0.125f), 0), 63);
    int y2 = min(max((int)ceilf (bx[3] * 0.125f), 0), 63);
    if (x2 <= x1) x2 = min(x1 + 1, 64);
    if (y2 <= y1) y2 = min(y1 + 1, 64);
    int Lx = x2 - x1, Ly = y2 - y1;
    float wy[5];
    float vx[5][16];
    #pragma unroll
    for (int k = 0; k < 5; ++k) {
        int sx = x1 + (k * Lx) / 5;
        int ex = x1 + ((k + 1) * Lx + 4) / 5;
        int sy = y1 + (k * Ly) / 5;
        int ey = y1 + ((k + 1) * Ly + 4) / 5;
        wy[k] = (y >= sy && y < ey) ? 1.0f / (float)(ey - sy) : 0.0f;
        float ix = 1.0f / (float)(ex - sx);
        #pragma unroll
        for (int i = 0; i < 16; ++i) {
            int xi = x0 + i;
            vx[k][i] = (xi >= sx && xi < ex) ? ix : 0.0f;
        }
    }
    unsigned short* base = P + (size_t)b * MPAD * NPIX + y * FW + x0;
    #pragma unroll
    for (int p = 0; p < 5; ++p)
        #pragma unroll
        for (int q = 0; q < 5; ++q) {
            u8s o0v, o1v;
            #pragma unroll
            for (int i = 0; i < 8; ++i) {
                o0v[i] = f32_to_bf16(wy[p] * vx[q][i]);
                o1v[i] = f32_to_bf16(wy[p] * vx[q][8 + i]);
            }
            unsigned short* dst = base + (size_t)(mb + p * 5 + q) * NPIX;
            *(u8s*)(dst)     = o0v;
            *(u8s*)(dst + 8) = o1v;
        }
}

// ---------------- pool GEMM: out[br][c][bin] = P[m,:] . attr[c,:] ----------
// A = P rows m (256/batch), B = attr rows c, K = 4096 pixels.
__global__ __launch_bounds__(256) void pool_gemm(
        const unsigned short* __restrict__ P,
        const unsigned short* __restrict__ attr,
        float* __restrict__ out) {
    __shared__ __align__(16) unsigned short lds_a[128 * 32];
    __shared__ __align__(16) unsigned short lds_b[128 * 32];
    int t  = threadIdx.x;
    int m0 = blockIdx.x * 128;   // bin-row tile (0 or 128)
    int c0 = blockIdx.y * 128;   // channel tile
    int b  = blockIdx.z;
    int wave = t >> 6, lane = t & 63;
    int wm = wave & 1, wn = wave >> 1;
    int quad = lane >> 4, l16 = lane & 15;
    const unsigned short* Pb = P + (size_t)b * MPAD * NPIX;
    const unsigned short* ab = attr + (size_t)b * COUT * NPIX;

    v4f acc[4][4];
    #pragma unroll
    for (int i = 0; i < 4; ++i)
        #pragma unroll
        for (int j = 0; j < 4; ++j) acc[i][j] = (v4f)0.0f;

    int row = t >> 2;
    int colsw = (t & 3) ^ ((t >> 3) & 3);
    const unsigned short* ga0 = Pb + (size_t)(m0 + row) * NPIX + colsw * 8;
    const unsigned short* ga1 = Pb + (size_t)(m0 + row + 64) * NPIX + colsw * 8;
    const unsigned short* gb0 = ab + (size_t)(c0 + row) * NPIX + colsw * 8;
    const unsigned short* gb1 = ab + (size_t)(c0 + row + 64) * NPIX + colsw * 8;
    unsigned short* la0 = lds_a + wave * 512;
    unsigned short* la1 = lds_a + 2048 + wave * 512;
    unsigned short* lb0 = lds_b + wave * 512;
    unsigned short* lb1 = lds_b + 2048 + wave * 512;

    int csw = (l16 >> 1) & 3;

    for (int kt = 0; kt < NPIX / 32; ++kt) {
        __syncthreads();
        GLOAD_LDS16(ga0, la0);
        GLOAD_LDS16(ga1, la1);
        GLOAD_LDS16(gb0, lb0);
        GLOAD_LDS16(gb1, lb1);
        ga0 += 32; ga1 += 32; gb0 += 32; gb1 += 32;
        __syncthreads();

        v8s pA[4], pB[4];
        #pragma unroll
        for (int i = 0; i < 4; ++i)
            pA[i] = *(const v8s*)(lds_a + (wm * 64 + i * 16 + l16) * 32 + (quad ^ csw) * 8);
        #pragma unroll
        for (int j = 0; j < 4; ++j)
            pB[j] = *(const v8s*)(lds_b + (wn * 64 + j * 16 + l16) * 32 + (quad ^ csw) * 8);
        #pragma unroll
        for (int i = 0; i < 4; ++i)
            #pragma unroll
            for (int j = 0; j < 4; ++j)
                acc[i][j] = __builtin_amdgcn_mfma_f32_16x16x32_bf16(pA[i], pB[j], acc[i][j], 0, 0, 0);
    }

    // out[640 + ((b*10 + box)*512 + c)*25 + bin], m = box*25 + bin
    #pragma unroll
    for (int i = 0; i < 4; ++i) {
        #pragma unroll
        for (int r = 0; r < 4; ++r) {
            int mrow = m0 + wm * 64 + i * 16 + quad * 4 + r;
            if (mrow < 250) {
                int box = mrow / 25;
                int bin = mrow - box * 25;
                size_t base = 640 + (size_t)(b * NBOX + box) * (COUT * 25) + bin;
                #pragma unroll
                for (int j = 0; j < 4; ++j) {
                    int c = c0 + wn * 64 + j * 16 + l16;
                    out[base + (size_t)c * 25] = acc[i][j][r];
                }
            }
        }
    }
}

extern "C" void kernel_launch(void* const* d_in, const int* in_sizes, int n_in,
                              void* d_out, int out_size, void* d_ws, size_t ws_size,
                              hipStream_t stream) {
    const float* c3     = (const float*)d_in[0];
    const float* c4     = (const float*)d_in[1];
    const float* boxes  = (const float*)d_in[2];
    const float* w_conv = (const float*)d_in[3];
    const float* b_conv = (const float*)d_in[4];
    const float* bng    = (const float*)d_in[5];
    const float* bnb    = (const float*)d_in[6];
    const float* bnm    = (const float*)d_in[7];
    const float* bnv    = (const float*)d_in[8];
    float* out = (float*)d_out;

    char* ws = (char*)d_ws;
    // layout: fusedT bf16 [16][4096][1536] | wbf | scale | shift | attr bf16 [16][512][4096]
    // P bf16 [16][256][4096] (33.5 MB) ALIASES fusedT (dead after gemm; stream-ordered).
    unsigned short* fusedT = (unsigned short*)ws;                       // 201326592 B
    unsigned short* P      = (unsigned short*)ws;                       //  33554432 B (alias)
    unsigned short* wbf    = (unsigned short*)(ws + 201326592);         //   1572864 B
    float* scale           = (float*)(ws + 202899456);                  //      2048 B
    float* shift           = (float*)(ws + 202901504);                  //      2048 B
    unsigned short* attr   = (unsigned short*)(ws + 202903552);         //  67108864 B

    hipMemcpyAsync(d_out, d_in[2], 640 * sizeof(float), hipMemcpyDeviceToDevice, stream);
    prep_bn<<<1, 512, 0, stream>>>(bng, bnb, bnm, bnv, b_conv, scale, shift);
    conv_w<<<(COUT * CIN + 255) / 256, 256, 0, stream>>>(w_conv, wbf, COUT * CIN);
    build_fusedT<<<dim3(24, 64, 16), 256, 0, stream>>>(c3, c4, fusedT);
    gemm_bn_relu<<<dim3(32, 4, 16), 256, 0, stream>>>(wbf, fusedT, scale, shift, attr);
    build_P<<<160, 256, 0, stream>>>(boxes, P);
    pool_gemm<<<dim3(2, 4, 16), 256, 0, stream>>>(P, attr, out);
    (void)in_sizes; (void)n_in; (void)out_size; (void)ws_size;
}